// Round 2
// baseline (18008.435 us; speedup 1.0000x reference)
//
#include <hip/hip_runtime.h>
#include <hip/hip_bf16.h>
#include <stdint.h>

#define B_ 128
#define T_ 256
#define IN_ 512
#define H_ 1024
#define G4_ 4096
#define TC_ 64              // time chunk
#define NCHUNK_ (T_ / TC_)

typedef __bf16 bf16x8 __attribute__((ext_vector_type(8)));
typedef float f32x4 __attribute__((ext_vector_type(4)));

#define AS1U(p) ((const __attribute__((address_space(1))) unsigned int*)(p))
#define AS3U(p) ((__attribute__((address_space(3))) unsigned int*)(p))

__device__ __forceinline__ uint16_t f2bf(float f) {
  union { float f; uint32_t u; } v; v.f = f;
  uint32_t r = (v.u + 0x7fffu + ((v.u >> 16) & 1u)) >> 16;
  return (uint16_t)r;
}
__device__ __forceinline__ float bf2f(uint16_t h) {
  union { uint32_t u; float f; } v; v.u = ((uint32_t)h) << 16;
  return v.f;
}
__device__ __forceinline__ float sigmoid_f(float x) {
  return 1.f / (1.f + __expf(-x));
}
__device__ __forceinline__ float tanh_f(float x) {
  x = fminf(15.f, fmaxf(-15.f, x));
  float e = __expf(2.f * x);
  return (e - 1.f) / (e + 1.f);
}

// ---------------- prep kernels ----------------
__global__ void k_f32_to_bf16(const float* __restrict__ src, uint16_t* __restrict__ dst, int n) {
  int i = (blockIdx.x * blockDim.x + threadIdx.x) * 4;
  if (i >= n) return;
  float4 v = *(const float4*)(src + i);
  ushort4 o;
  o.x = f2bf(v.x); o.y = f2bf(v.y); o.z = f2bf(v.z); o.w = f2bf(v.w);
  *(ushort4*)(dst + i) = o;
}

__global__ void k_bias(const float* __restrict__ a, const float* __restrict__ b, float* __restrict__ o) {
  int i = blockIdx.x * blockDim.x + threadIdx.x;
  if (i < G4_) o[i] = a[i] + b[i];
}

// Rearrange w_hh (fp32 [4096][1024]) into per-slice MFMA B-fragments, bf16:
// dst[s][nt][ks][lane][j] = w_hh[1024*nt + 16*s + (lane&15)][ks*32 + (lane>>4)*8 + j]
__global__ void k_whh_frag(const float* __restrict__ whh, uint16_t* __restrict__ dst) {
  int tid = blockIdx.x * blockDim.x + threadIdx.x;   // 0..524287
  int lane = tid & 63;
  int ks = (tid >> 6) & 31;
  int nt = (tid >> 11) & 3;
  int s  = tid >> 13;
  int row = nt * 1024 + s * 16 + (lane & 15);
  int col = ks * 32 + ((lane >> 4) << 3);
  const float* sp = whh + (size_t)row * H_ + col;
  uint16_t o[8];
  #pragma unroll
  for (int j = 0; j < 8; ++j) o[j] = f2bf(sp[j]);
  uint4 pk;
  __builtin_memcpy(&pk, o, 16);
  *(uint4*)(dst + (size_t)tid * 8) = pk;
}

// ---------------- input-projection GEMM ----------------
__global__ __launch_bounds__(256, 1) void k_gemm_xp(
    const uint16_t* __restrict__ A, const uint16_t* __restrict__ W,
    const float* __restrict__ bias, uint16_t* __restrict__ xp,
    int K, int t0)
{
  __shared__ __align__(16) uint16_t As[128 * 32];
  __shared__ __align__(16) uint16_t Bs[128 * 32];
  const int tid = threadIdx.x;
  const int l = tid & 63;
  const int w = tid >> 6;
  const int mx = blockIdx.x;
  const int n0 = blockIdx.y * 128;
  const int wm = (w >> 1) * 64;
  const int wn = (w & 1) * 64;

  f32x4 acc[4][4] = {};

  for (int k0 = 0; k0 < K; k0 += 32) {
    __syncthreads();
    #pragma unroll
    for (int it = 0; it < 2; ++it) {
      const int chunk = w * 2 + it;
      const int loff = chunk * 1024 + l * 16;  // byte offset in tile
      const int row = loff >> 6;               // 0..127
      const int colb = loff & 63;
      const int gm = mx * 512 + t0 + ((row >> 6) << 8) + (row & 63);
      const uint16_t* ga = A + (size_t)gm * K + k0 + (colb >> 1);
      __builtin_amdgcn_global_load_lds(AS1U(ga), AS3U((char*)As + chunk * 1024), 16, 0, 0);
      const uint16_t* gb = W + (size_t)(n0 + row) * K + k0 + (colb >> 1);
      __builtin_amdgcn_global_load_lds(AS1U(gb), AS3U((char*)Bs + chunk * 1024), 16, 0, 0);
    }
    __syncthreads();
    bf16x8 af[4], bfr[4];
    #pragma unroll
    for (int i = 0; i < 4; ++i)
      af[i] = *(const bf16x8*)&As[(wm + i * 16 + (l & 15)) * 32 + ((l >> 4) << 3)];
    #pragma unroll
    for (int j = 0; j < 4; ++j)
      bfr[j] = *(const bf16x8*)&Bs[(wn + j * 16 + (l & 15)) * 32 + ((l >> 4) << 3)];
    #pragma unroll
    for (int i = 0; i < 4; ++i) {
      #pragma unroll
      for (int j = 0; j < 4; ++j)
        acc[i][j] = __builtin_amdgcn_mfma_f32_16x16x32_bf16(af[i], bfr[j], acc[i][j], 0, 0, 0);
    }
  }

  #pragma unroll
  for (int i = 0; i < 4; ++i) {
    const int mbase = wm + i * 16 + ((l >> 4) << 2);
    #pragma unroll
    for (int j = 0; j < 4; ++j) {
      const int ncol = n0 + wn + j * 16 + (l & 15);
      const float bv = bias[ncol];
      #pragma unroll
      for (int r = 0; r < 4; ++r) {
        const int mrow = mbase + r;                      // 0..127
        const size_t xrow = (size_t)mx * 128 + mrow;     // == b*TC + tl
        xp[xrow * G4_ + ncol] = f2bf(acc[i][j][r] + bv);
      }
    }
  }
}

// ---------------- persistent LSTM recurrence ----------------
// grid = 256 blocks x 1024 threads (16 waves, 4/SIMD). 4 batch groups x 64 slice-blocks.
// Block (g,s): samples 32g..32g+31, hidden units 16s..16s+15.
// Wave w: mt = w&1 (16-sample half), np = (w>>1)&3 (gate), kh = w>>3 (K-half).
// w_hh slice resident in LDS; c in registers; h via global double buffer;
// sync via per-block flag array + all-lane poll (device scope, agent fences).
__global__ __launch_bounds__(1024, 4) void k_lstm(
    const uint16_t* __restrict__ whhf, const uint16_t* __restrict__ xp,
    uint16_t* __restrict__ seq, uint16_t* __restrict__ hbuf,
    float* __restrict__ cbuf, unsigned int* __restrict__ flags, int t0)
{
  __shared__ __align__(16) uint16_t wlds[4 * 32 * 64 * 8];  // 128 KiB
  __shared__ float part[2][32][65];                         // 16.6 KiB
  const int tid = threadIdx.x;
  const int l = tid & 63;
  const int w = tid >> 6;          // 0..15
  const int mt = w & 1;
  const int np = (w >> 1) & 3;
  const int kh = w >> 3;           // K-half
  const int bid = blockIdx.x;
  const int g = (bid & 7) >> 1;                 // XCD-pair group
  const int s = ((bid >> 3) << 1) | (bid & 1);  // slice 0..63

  {
    const uint4* src = (const uint4*)(whhf + (size_t)s * (4 * 32 * 64 * 8));
    uint4* dst = (uint4*)wlds;
    #pragma unroll
    for (int i = 0; i < 8; ++i) dst[tid + i * 1024] = src[tid + i * 1024];
  }

  const int u = tid & 15;
  const int sm = tid >> 4;         // sample-in-group (valid < 32 for tid < 512)
  float c0 = 0.f;
  if (tid < 512) c0 = cbuf[(size_t)(g * 32 + sm) * H_ + s * 16 + u];

  const int samp = g * 32 + mt * 16 + (l & 15);
  const uint16_t* bbase = wlds + np * (32 * 64 * 8) + (kh * 16) * (64 * 8) + l * 8;
  unsigned int* gflag = flags + g * 64;

  __syncthreads();

  for (int tl = 0; tl < TC_; ++tl) {
    const int par = tl & 1;
    // xp prefetch (independent of h_t -> hides under MFMA phase)
    uint16_t xr0 = 0, xr1 = 0, xr2 = 0, xr3 = 0;
    if (tid < 512) {
      const uint16_t* xpr = xp + ((size_t)(g * 32 + sm) * TC_ + tl) * G4_ + s * 16 + u;
      xr0 = xpr[0]; xr1 = xpr[1024]; xr2 = xpr[2048]; xr3 = xpr[3072];
    }
    const uint16_t* arow = hbuf + (size_t)par * (B_ * H_) + (size_t)samp * H_
                           + ((l >> 4) << 3) + kh * 512;
    f32x4 e0 = {0.f, 0.f, 0.f, 0.f};
    f32x4 e1 = {0.f, 0.f, 0.f, 0.f};
    #pragma unroll
    for (int kk = 0; kk < 16; kk += 2) {
      bf16x8 av0 = *(const bf16x8*)(arow + kk * 32);
      bf16x8 av1 = *(const bf16x8*)(arow + kk * 32 + 32);
      bf16x8 bv0 = *(const bf16x8*)(bbase + kk * (64 * 8));
      bf16x8 bv1 = *(const bf16x8*)(bbase + (kk + 1) * (64 * 8));
      e0 = __builtin_amdgcn_mfma_f32_16x16x32_bf16(av0, bv0, e0, 0, 0, 0);
      e1 = __builtin_amdgcn_mfma_f32_16x16x32_bf16(av1, bv1, e1, 0, 0, 0);
    }
    f32x4 e = e0 + e1;
    #pragma unroll
    for (int r = 0; r < 4; ++r)
      part[kh][mt * 16 + ((l >> 4) << 2) + r][np * 16 + (l & 15)] = e[r];
    __syncthreads();
    if (tid < 512) {
      float gi = part[0][sm][u]      + part[1][sm][u]      + bf2f(xr0);
      float gf = part[0][sm][16 + u] + part[1][sm][16 + u] + bf2f(xr1);
      float gg = part[0][sm][32 + u] + part[1][sm][32 + u] + bf2f(xr2);
      float go = part[0][sm][48 + u] + part[1][sm][48 + u] + bf2f(xr3);
      c0 = sigmoid_f(gf) * c0 + sigmoid_f(gi) * tanh_f(gg);
      float hh = sigmoid_f(go) * tanh_f(c0);
      uint16_t hb = f2bf(hh);
      const int b = g * 32 + sm;
      hbuf[(size_t)(1 - par) * (B_ * H_) + (size_t)b * H_ + s * 16 + u] = hb;
      seq[((size_t)b * T_ + (t0 + tl)) * H_ + s * 16 + u] = hb;
    }
    __syncthreads();
    if (tid == 0) {
      __threadfence();   // agent release: drain stores + write back L2
      __hip_atomic_store(gflag + s, (unsigned)(tl + 1),
                         __ATOMIC_RELAXED, __HIP_MEMORY_SCOPE_AGENT);
    }
    if (w == 0) {
      const unsigned tgt = (unsigned)(tl + 1);
      while (__hip_atomic_load(gflag + l, __ATOMIC_RELAXED,
                               __HIP_MEMORY_SCOPE_AGENT) < tgt)
        __builtin_amdgcn_s_sleep(1);
      __builtin_amdgcn_fence(__ATOMIC_ACQUIRE, "agent");  // invalidate stale lines
    }
    __syncthreads();
  }
  if (tid < 512) cbuf[(size_t)(g * 32 + sm) * H_ + s * 16 + u] = c0;
}

// ---------------- MLP head ----------------
__global__ __launch_bounds__(256) void k_mlp(
    const uint16_t* __restrict__ seq2,
    const float* __restrict__ w1, const float* __restrict__ b1,
    const float* __restrict__ w2, const float* __restrict__ b2,
    float* __restrict__ out)
{
  __shared__ float hv[H_];
  __shared__ float part[32][8];
  __shared__ float hid[32];
  const int b = blockIdx.x, tid = threadIdx.x;
  const uint16_t* hrow = seq2 + ((size_t)b * T_ + (T_ - 1)) * H_;
  for (int i = tid; i < H_; i += 256) hv[i] = bf2f(hrow[i]);
  __syncthreads();
  const int j = tid >> 3, p = tid & 7;
  float sum = 0.f;
  const float* wr = w1 + (size_t)j * H_ + p * 128;
  const float* hp = hv + p * 128;
  for (int k = 0; k < 128; ++k) sum += wr[k] * hp[k];
  part[j][p] = sum;
  __syncthreads();
  if (tid < 32) {
    float s2 = 0.f;
    #pragma unroll
    for (int pp = 0; pp < 8; ++pp) s2 += part[tid][pp];
    hid[tid] = fmaxf(s2 + b1[tid], 0.f);
  }
  __syncthreads();
  if (tid < 10) {
    float o = b2[tid];
    #pragma unroll
    for (int jj = 0; jj < 32; ++jj) o += hid[jj] * w2[tid * 32 + jj];
    out[b * 10 + tid] = o;
  }
}

// ---------------- launch ----------------
extern "C" void kernel_launch(void* const* d_in, const int* in_sizes, int n_in,
                              void* d_out, int out_size, void* d_ws, size_t ws_size,
                              hipStream_t stream)
{
  const float* x = (const float*)d_in[0];
  const float* w_ih[3] = {(const float*)d_in[1], (const float*)d_in[5], (const float*)d_in[9]};
  const float* w_hh[3] = {(const float*)d_in[2], (const float*)d_in[6], (const float*)d_in[10]};
  const float* b_ih[3] = {(const float*)d_in[3], (const float*)d_in[7], (const float*)d_in[11]};
  const float* b_hh[3] = {(const float*)d_in[4], (const float*)d_in[8], (const float*)d_in[12]};
  const float* w1 = (const float*)d_in[13];
  const float* b1 = (const float*)d_in[14];
  const float* w2 = (const float*)d_in[15];
  const float* b2 = (const float*)d_in[16];
  float* out = (float*)d_out;

  char* ws = (char*)d_ws;
  size_t off = 0;
  auto alloc = [&](size_t bytes) {
    char* p = ws + off;
    off += (bytes + 255) & ~(size_t)255;
    return p;
  };
  uint16_t* XBF  = (uint16_t*)alloc((size_t)B_ * T_ * IN_ * 2);
  uint16_t* WIH0 = (uint16_t*)alloc((size_t)G4_ * IN_ * 2);
  uint16_t* WIH1 = (uint16_t*)alloc((size_t)G4_ * H_ * 2);
  uint16_t* WIH2 = (uint16_t*)alloc((size_t)G4_ * H_ * 2);
  float*    BIAS = (float*)alloc((size_t)3 * G4_ * 4);
  uint16_t* WHHF = (uint16_t*)alloc((size_t)3 * G4_ * H_ * 2);
  uint16_t* XP   = (uint16_t*)alloc((size_t)B_ * TC_ * G4_ * 2);
  uint16_t* SEQ  = (uint16_t*)alloc((size_t)B_ * T_ * H_ * 2);
  uint16_t* HBUF = (uint16_t*)alloc((size_t)2 * B_ * H_ * 2);
  float*    CBUF = (float*)alloc((size_t)B_ * H_ * 4);
  unsigned int* FLG = (unsigned int*)alloc((size_t)3 * NCHUNK_ * 1024 * 4);

  hipMemsetAsync(FLG, 0, (size_t)3 * NCHUNK_ * 1024 * 4, stream);

  int n;
  n = B_ * T_ * IN_;
  k_f32_to_bf16<<<n / 4 / 256, 256, 0, stream>>>(x, XBF, n);
  n = G4_ * IN_;
  k_f32_to_bf16<<<n / 4 / 256, 256, 0, stream>>>(w_ih[0], WIH0, n);
  n = G4_ * H_;
  k_f32_to_bf16<<<n / 4 / 256, 256, 0, stream>>>(w_ih[1], WIH1, n);
  k_f32_to_bf16<<<n / 4 / 256, 256, 0, stream>>>(w_ih[2], WIH2, n);
  for (int li = 0; li < 3; ++li)
    k_bias<<<16, 256, 0, stream>>>(b_ih[li], b_hh[li], BIAS + li * G4_);
  for (int li = 0; li < 3; ++li)
    k_whh_frag<<<2048, 256, 0, stream>>>(w_hh[li], WHHF + (size_t)li * G4_ * H_);

  const uint16_t* seq_in[3] = {XBF, SEQ, SEQ};
  const uint16_t* wih[3] = {WIH0, WIH1, WIH2};
  const int Ks[3] = {IN_, H_, H_};

  for (int li = 0; li < 3; ++li) {
    hipMemsetAsync(HBUF, 0, (size_t)2 * B_ * H_ * 2, stream);
    hipMemsetAsync(CBUF, 0, (size_t)B_ * H_ * 4, stream);
    for (int c = 0; c < NCHUNK_; ++c) {
      dim3 grid(64, 32);
      k_gemm_xp<<<grid, 256, 0, stream>>>(seq_in[li], wih[li], BIAS + li * G4_, XP,
                                          Ks[li], c * TC_);
      unsigned int* flg_lc = FLG + (size_t)(li * NCHUNK_ + c) * 1024;
      k_lstm<<<256, 1024, 0, stream>>>(WHHF + (size_t)li * G4_ * H_, XP, SEQ, HBUF,
                                       CBUF, flg_lc, c * TC_);
    }
  }
  k_mlp<<<B_, 256, 0, stream>>>(SEQ, w1, b1, w2, b2, out);
}

// Round 3
// 4106.027 us; speedup vs baseline: 4.3859x; 4.3859x over previous
//
#include <hip/hip_runtime.h>
#include <hip/hip_bf16.h>
#include <stdint.h>

#define B_ 128
#define T_ 256
#define IN_ 512
#define H_ 1024
#define G4_ 4096
#define TC_ 64              // time chunk
#define NCHUNK_ (T_ / TC_)

typedef __bf16 bf16x8 __attribute__((ext_vector_type(8)));
typedef float f32x4 __attribute__((ext_vector_type(4)));

#define AS1U(p) ((const __attribute__((address_space(1))) unsigned int*)(p))
#define AS3U(p) ((__attribute__((address_space(3))) unsigned int*)(p))

__device__ __forceinline__ uint16_t f2bf(float f) {
  union { float f; uint32_t u; } v; v.f = f;
  uint32_t r = (v.u + 0x7fffu + ((v.u >> 16) & 1u)) >> 16;
  return (uint16_t)r;
}
__device__ __forceinline__ float bf2f(uint16_t h) {
  union { uint32_t u; float f; } v; v.u = ((uint32_t)h) << 16;
  return v.f;
}
__device__ __forceinline__ float sigmoid_f(float x) {
  return 1.f / (1.f + __expf(-x));
}
__device__ __forceinline__ float tanh_f(float x) {
  x = fminf(15.f, fmaxf(-15.f, x));
  float e = __expf(2.f * x);
  return (e - 1.f) / (e + 1.f);
}

// ---------------- prep kernels ----------------
__global__ void k_f32_to_bf16(const float* __restrict__ src, uint16_t* __restrict__ dst, int n) {
  int i = (blockIdx.x * blockDim.x + threadIdx.x) * 4;
  if (i >= n) return;
  float4 v = *(const float4*)(src + i);
  ushort4 o;
  o.x = f2bf(v.x); o.y = f2bf(v.y); o.z = f2bf(v.z); o.w = f2bf(v.w);
  *(ushort4*)(dst + i) = o;
}

__global__ void k_bias(const float* __restrict__ a, const float* __restrict__ b, float* __restrict__ o) {
  int i = blockIdx.x * blockDim.x + threadIdx.x;
  if (i < G4_) o[i] = a[i] + b[i];
}

// Rearrange w_hh (fp32 [4096][1024]) into per-(slice,wave) MFMA B-fragments, bf16.
// Block s5 owns units U0=s5*32..+31; wave w: nt=w&7 (n-tile: gate q=nt>>1, sub=nt&1), kh=w>>3.
// dst[((s5*16+w)*16+kk)*512 + lane*8 + j] =
//   w_hh[(nt>>1)*1024 + s5*32 + (nt&1)*16 + (lane&15)][kh*512 + kk*32 + (lane>>4)*8 + j]
__global__ void k_whh_frag(const float* __restrict__ whh, uint16_t* __restrict__ dst) {
  int t = blockIdx.x * blockDim.x + threadIdx.x;   // 0..524287
  int lane = t & 63;
  int kk = (t >> 6) & 15;
  int w  = (t >> 10) & 15;
  int s5 = t >> 14;
  int nt = w & 7, kh = w >> 3;
  int row = (nt >> 1) * 1024 + s5 * 32 + (nt & 1) * 16 + (lane & 15);
  int col = kh * 512 + kk * 32 + ((lane >> 4) << 3);
  const float* sp = whh + (size_t)row * H_ + col;
  uint16_t o[8];
  #pragma unroll
  for (int j = 0; j < 8; ++j) o[j] = f2bf(sp[j]);
  uint4 pk;
  __builtin_memcpy(&pk, o, 16);
  *(uint4*)(dst + (size_t)t * 8) = pk;
}

// ---------------- input-projection GEMM ----------------
__global__ __launch_bounds__(256, 1) void k_gemm_xp(
    const uint16_t* __restrict__ A, const uint16_t* __restrict__ W,
    const float* __restrict__ bias, uint16_t* __restrict__ xp,
    int K, int t0)
{
  __shared__ __align__(16) uint16_t As[128 * 32];
  __shared__ __align__(16) uint16_t Bs[128 * 32];
  const int tid = threadIdx.x;
  const int l = tid & 63;
  const int w = tid >> 6;
  const int mx = blockIdx.x;
  const int n0 = blockIdx.y * 128;
  const int wm = (w >> 1) * 64;
  const int wn = (w & 1) * 64;

  f32x4 acc[4][4] = {};

  for (int k0 = 0; k0 < K; k0 += 32) {
    __syncthreads();
    #pragma unroll
    for (int it = 0; it < 2; ++it) {
      const int chunk = w * 2 + it;
      const int loff = chunk * 1024 + l * 16;  // byte offset in tile
      const int row = loff >> 6;               // 0..127
      const int colb = loff & 63;
      const int gm = mx * 512 + t0 + ((row >> 6) << 8) + (row & 63);
      const uint16_t* ga = A + (size_t)gm * K + k0 + (colb >> 1);
      __builtin_amdgcn_global_load_lds(AS1U(ga), AS3U((char*)As + chunk * 1024), 16, 0, 0);
      const uint16_t* gb = W + (size_t)(n0 + row) * K + k0 + (colb >> 1);
      __builtin_amdgcn_global_load_lds(AS1U(gb), AS3U((char*)Bs + chunk * 1024), 16, 0, 0);
    }
    __syncthreads();
    bf16x8 af[4], bfr[4];
    #pragma unroll
    for (int i = 0; i < 4; ++i)
      af[i] = *(const bf16x8*)&As[(wm + i * 16 + (l & 15)) * 32 + ((l >> 4) << 3)];
    #pragma unroll
    for (int j = 0; j < 4; ++j)
      bfr[j] = *(const bf16x8*)&Bs[(wn + j * 16 + (l & 15)) * 32 + ((l >> 4) << 3)];
    #pragma unroll
    for (int i = 0; i < 4; ++i) {
      #pragma unroll
      for (int j = 0; j < 4; ++j)
        acc[i][j] = __builtin_amdgcn_mfma_f32_16x16x32_bf16(af[i], bfr[j], acc[i][j], 0, 0, 0);
    }
  }

  #pragma unroll
  for (int i = 0; i < 4; ++i) {
    const int mbase = wm + i * 16 + ((l >> 4) << 2);
    #pragma unroll
    for (int j = 0; j < 4; ++j) {
      const int ncol = n0 + wn + j * 16 + (l & 15);
      const float bv = bias[ncol];
      #pragma unroll
      for (int r = 0; r < 4; ++r) {
        const int mrow = mbase + r;                      // 0..127
        const size_t xrow = (size_t)mx * 128 + mrow;     // == b*TC + tl
        xp[xrow * G4_ + ncol] = f2bf(acc[i][j][r] + bv);
      }
    }
  }
}

// ---------------- persistent LSTM recurrence ----------------
// 256 blocks x 1024 thr. 8 groups (g=bid&7) x 16 samples; 32 blocks/group (s5=bid>>3),
// block owns units U0=s5*32..+31. w_hh B-fragments resident in VGPRs (64/lane).
// h exchanged via SYSTEM-scope (write-through, MALL-coherent) stores/loads -> no
// wbl2/inv fences, placement-independent. h staged per step into XOR-swizzled LDS.
// LDS padded >80KB to force 1 block/CU (all 256 blocks co-resident).
__global__ __launch_bounds__(1024, 4) void k_lstm(
    const uint16_t* __restrict__ whhf, const uint16_t* __restrict__ xp,
    uint16_t* __restrict__ seq, uint32_t* __restrict__ hbuf,
    float* __restrict__ cbuf, unsigned int* __restrict__ flags, int t0)
{
  __shared__ __align__(16) uint16_t hstg[48 * 1024];   // 96KB declared; first 32KB used
  __shared__ float part[2][8][16][17];                 // 8.7KB
  const int tid = threadIdx.x;
  const int l = tid & 63;
  const int w = tid >> 6;           // 0..15
  const int nt = w & 7;
  const int kh = w >> 3;
  const int bid = blockIdx.x;
  const int g = bid & 7;
  const int s5 = bid >> 3;          // 0..31
  const int U0 = s5 * 32;
  const int gs0 = g * 16;

  // resident weight fragments
  bf16x8 bfr[16];
  {
    const uint16_t* wp = whhf + (size_t)(s5 * 16 + w) * 8192 + l * 8;
    #pragma unroll
    for (int kk = 0; kk < 16; ++kk)
      bfr[kk] = *(const bf16x8*)(wp + kk * 512);
  }

  const int u = tid & 31;
  const int smg = (tid >> 5) & 15;
  float cc = 0.f;
  if (tid < 512) cc = cbuf[(size_t)(gs0 + smg) * H_ + U0 + u];

  uint16_t x0 = 0, x1 = 0, x2 = 0, x3 = 0;
  if (tid < 512) {
    const uint16_t* p = xp + ((size_t)(gs0 + smg) * TC_ + 0) * G4_ + U0 + u;
    x0 = p[0]; x1 = p[1024]; x2 = p[2048]; x3 = p[3072];
  }

  unsigned int* gflag = flags + g * 32;

  auto stage_h = [&](int par) {
    uint64_t* src = (uint64_t*)((char*)hbuf + (size_t)par * (B_ * H_ * 2));
    #pragma unroll
    for (int pass = 0; pass < 2; ++pass) {
      int ci = pass * 1024 + tid;
      int smc = ci >> 7, uc = ci & 127;
      uint64_t* sp = src + ((size_t)(gs0 + smc) * 2048 + (size_t)uc * 16) / 8;
      uint64_t a = __hip_atomic_load(sp,     __ATOMIC_RELAXED, __HIP_MEMORY_SCOPE_SYSTEM);
      uint64_t b = __hip_atomic_load(sp + 1, __ATOMIC_RELAXED, __HIP_MEMORY_SCOPE_SYSTEM);
      int dst = smc * 2048 + ((uc * 16) ^ ((smc & 7) << 4));
      *(uint64_t*)((char*)hstg + dst) = a;
      *(uint64_t*)((char*)hstg + dst + 8) = b;
    }
  };

  stage_h(0);
  __syncthreads();

  for (int tl = 0; tl < TC_; ++tl) {
    // ---- MFMA phase: A from swizzled LDS, B resident ----
    f32x4 acc = {0.f, 0.f, 0.f, 0.f};
    const int smA = l & 15;
    const int colbase = kh * 1024 + ((l >> 4) << 4);   // bytes within h row
    #pragma unroll
    for (int kk = 0; kk < 16; ++kk) {
      const int cb = colbase + kk * 64;
      bf16x8 av = *(const bf16x8*)((const char*)hstg + smA * 2048 + (cb ^ ((smA & 7) << 4)));
      acc = __builtin_amdgcn_mfma_f32_16x16x32_bf16(av, bfr[kk], acc, 0, 0, 0);
    }
    #pragma unroll
    for (int r = 0; r < 4; ++r)
      part[kh][nt][((l >> 4) << 2) + r][l & 15] = acc[r];
    __syncthreads();

    // ---- gate phase (waves 0..7) ----
    if (tid < 512) {
      const int sub = u >> 4, uc = u & 15;
      float gi = part[0][0 + sub][smg][uc] + part[1][0 + sub][smg][uc] + bf2f(x0);
      float gf = part[0][2 + sub][smg][uc] + part[1][2 + sub][smg][uc] + bf2f(x1);
      float gg = part[0][4 + sub][smg][uc] + part[1][4 + sub][smg][uc] + bf2f(x2);
      float go = part[0][6 + sub][smg][uc] + part[1][6 + sub][smg][uc] + bf2f(x3);
      cc = sigmoid_f(gf) * cc + sigmoid_f(gi) * tanh_f(gg);
      float hh = sigmoid_f(go) * tanh_f(cc);
      uint16_t hb = f2bf(hh);
      if (tl + 1 < TC_) {   // prefetch next xp while stores/poll happen
        const uint16_t* p = xp + ((size_t)(gs0 + smg) * TC_ + tl + 1) * G4_ + U0 + u;
        x0 = p[0]; x1 = p[1024]; x2 = p[2048]; x3 = p[3072];
      }
      unsigned int o = (unsigned int)__shfl_xor((int)(unsigned int)hb, 1);
      if ((u & 1) == 0) {
        uint32_t pk = (uint32_t)hb | (o << 16);
        const int b = gs0 + smg;
        uint32_t* hp = hbuf + (size_t)(1 - (tl & 1)) * (B_ * H_ / 2)
                            + ((size_t)b * H_ + U0 + u) / 2;
        __hip_atomic_store(hp, pk, __ATOMIC_RELAXED, __HIP_MEMORY_SCOPE_SYSTEM);
        uint32_t* sq = (uint32_t*)seq + (((size_t)b * T_ + (t0 + tl)) * H_ + U0 + u) / 2;
        *sq = pk;
      }
    }
    __syncthreads();   // drains vmcnt(0): h stores visible at coherence point
    if (tid == 0)
      __hip_atomic_store(gflag + s5, (unsigned)(tl + 1),
                         __ATOMIC_RELAXED, __HIP_MEMORY_SCOPE_SYSTEM);
    if (tid < 32) {
      const unsigned tgt = (unsigned)(tl + 1);
      while (__hip_atomic_load(gflag + tid, __ATOMIC_RELAXED,
                               __HIP_MEMORY_SCOPE_SYSTEM) < tgt)
        __builtin_amdgcn_s_sleep(1);
    }
    __syncthreads();
    if (tl + 1 < TC_) {
      stage_h((tl + 1) & 1);
      __syncthreads();
    }
  }
  if (tid < 512) cbuf[(size_t)(gs0 + smg) * H_ + U0 + u] = cc;
}

// ---------------- MLP head ----------------
__global__ __launch_bounds__(256) void k_mlp(
    const uint16_t* __restrict__ seq2,
    const float* __restrict__ w1, const float* __restrict__ b1,
    const float* __restrict__ w2, const float* __restrict__ b2,
    float* __restrict__ out)
{
  __shared__ float hv[H_];
  __shared__ float part[32][8];
  __shared__ float hid[32];
  const int b = blockIdx.x, tid = threadIdx.x;
  const uint16_t* hrow = seq2 + ((size_t)b * T_ + (T_ - 1)) * H_;
  for (int i = tid; i < H_; i += 256) hv[i] = bf2f(hrow[i]);
  __syncthreads();
  const int j = tid >> 3, p = tid & 7;
  float sum = 0.f;
  const float* wr = w1 + (size_t)j * H_ + p * 128;
  const float* hp = hv + p * 128;
  for (int k = 0; k < 128; ++k) sum += wr[k] * hp[k];
  part[j][p] = sum;
  __syncthreads();
  if (tid < 32) {
    float s2 = 0.f;
    #pragma unroll
    for (int pp = 0; pp < 8; ++pp) s2 += part[tid][pp];
    hid[tid] = fmaxf(s2 + b1[tid], 0.f);
  }
  __syncthreads();
  if (tid < 10) {
    float o = b2[tid];
    #pragma unroll
    for (int jj = 0; jj < 32; ++jj) o += hid[jj] * w2[tid * 32 + jj];
    out[b * 10 + tid] = o;
  }
}

// ---------------- launch ----------------
extern "C" void kernel_launch(void* const* d_in, const int* in_sizes, int n_in,
                              void* d_out, int out_size, void* d_ws, size_t ws_size,
                              hipStream_t stream)
{
  const float* x = (const float*)d_in[0];
  const float* w_ih[3] = {(const float*)d_in[1], (const float*)d_in[5], (const float*)d_in[9]};
  const float* w_hh[3] = {(const float*)d_in[2], (const float*)d_in[6], (const float*)d_in[10]};
  const float* b_ih[3] = {(const float*)d_in[3], (const float*)d_in[7], (const float*)d_in[11]};
  const float* b_hh[3] = {(const float*)d_in[4], (const float*)d_in[8], (const float*)d_in[12]};
  const float* w1 = (const float*)d_in[13];
  const float* b1 = (const float*)d_in[14];
  const float* w2 = (const float*)d_in[15];
  const float* b2 = (const float*)d_in[16];
  float* out = (float*)d_out;

  char* ws = (char*)d_ws;
  size_t off = 0;
  auto alloc = [&](size_t bytes) {
    char* p = ws + off;
    off += (bytes + 255) & ~(size_t)255;
    return p;
  };
  uint16_t* XBF  = (uint16_t*)alloc((size_t)B_ * T_ * IN_ * 2);
  uint16_t* WIH0 = (uint16_t*)alloc((size_t)G4_ * IN_ * 2);
  uint16_t* WIH1 = (uint16_t*)alloc((size_t)G4_ * H_ * 2);
  uint16_t* WIH2 = (uint16_t*)alloc((size_t)G4_ * H_ * 2);
  float*    BIAS = (float*)alloc((size_t)3 * G4_ * 4);
  uint16_t* WHHF = (uint16_t*)alloc((size_t)3 * G4_ * H_ * 2);
  uint16_t* XP   = (uint16_t*)alloc((size_t)B_ * TC_ * G4_ * 2);
  uint16_t* SEQ  = (uint16_t*)alloc((size_t)B_ * T_ * H_ * 2);
  uint32_t* HBUF = (uint32_t*)alloc((size_t)2 * B_ * H_ * 2);
  float*    CBUF = (float*)alloc((size_t)B_ * H_ * 4);
  unsigned int* FLG = (unsigned int*)alloc((size_t)3 * NCHUNK_ * 1024 * 4);

  hipMemsetAsync(FLG, 0, (size_t)3 * NCHUNK_ * 1024 * 4, stream);

  int n;
  n = B_ * T_ * IN_;
  k_f32_to_bf16<<<n / 4 / 256, 256, 0, stream>>>(x, XBF, n);
  n = G4_ * IN_;
  k_f32_to_bf16<<<n / 4 / 256, 256, 0, stream>>>(w_ih[0], WIH0, n);
  n = G4_ * H_;
  k_f32_to_bf16<<<n / 4 / 256, 256, 0, stream>>>(w_ih[1], WIH1, n);
  k_f32_to_bf16<<<n / 4 / 256, 256, 0, stream>>>(w_ih[2], WIH2, n);
  for (int li = 0; li < 3; ++li)
    k_bias<<<16, 256, 0, stream>>>(b_ih[li], b_hh[li], BIAS + li * G4_);
  for (int li = 0; li < 3; ++li)
    k_whh_frag<<<2048, 256, 0, stream>>>(w_hh[li], WHHF + (size_t)li * G4_ * H_);

  const uint16_t* seq_in[3] = {XBF, SEQ, SEQ};
  const uint16_t* wih[3] = {WIH0, WIH1, WIH2};
  const int Ks[3] = {IN_, H_, H_};

  for (int li = 0; li < 3; ++li) {
    hipMemsetAsync(HBUF, 0, (size_t)2 * B_ * H_ * 2, stream);
    hipMemsetAsync(CBUF, 0, (size_t)B_ * H_ * 4, stream);
    for (int c = 0; c < NCHUNK_; ++c) {
      dim3 grid(64, 32);
      k_gemm_xp<<<grid, 256, 0, stream>>>(seq_in[li], wih[li], BIAS + li * G4_, XP,
                                          Ks[li], c * TC_);
      unsigned int* flg_lc = FLG + (size_t)(li * NCHUNK_ + c) * 1024;
      k_lstm<<<256, 1024, 0, stream>>>(WHHF + (size_t)li * G4_ * H_, XP, SEQ, HBUF,
                                       CBUF, flg_lc, c * TC_);
    }
  }
  k_mlp<<<B_, 256, 0, stream>>>(SEQ, w1, b1, w2, b2, out);
}